// Round 4
// baseline (300.283 us; speedup 1.0000x reference)
//
#include <hip/hip_runtime.h>

typedef unsigned short ushort_t;
typedef __attribute__((ext_vector_type(8))) short short8;
typedef __attribute__((ext_vector_type(4))) short bf16x4;
typedef __attribute__((ext_vector_type(4))) float floatx4;

#define MFMA32(A, B, C) __builtin_amdgcn_mfma_f32_16x16x32_bf16(A, B, C, 0, 0, 0)

__device__ __forceinline__ float exp2_(float x) {
#if __has_builtin(__builtin_amdgcn_exp2f)
  return __builtin_amdgcn_exp2f(x);
#else
  return __builtin_exp2f(x);
#endif
}

__device__ __forceinline__ unsigned short f2bf(float f) {
  unsigned int u = __float_as_uint(f);
  u += 0x7fffu + ((u >> 16) & 1u);
  return (unsigned short)(u >> 16);
}

__device__ __forceinline__ void gl_lds16(const void* g, void* l) {
  __builtin_amdgcn_global_load_lds((const __attribute__((address_space(1))) void*)g,
                                   (__attribute__((address_space(3))) void*)l,
                                   16, 0, 0);
}

// 0.125 (1/sqrt(64)) * log2(e): scores land in log2 domain for v_exp_f32
#define QSCALE 0.18033688011112042f

// ---------------- prep kernels ----------------

__global__ void conv_x_kernel(const float* __restrict__ src, ushort_t* __restrict__ dst, int n4) {
  int i = blockIdx.x * blockDim.x + threadIdx.x;
  if (i >= n4) return;
  float4 v = ((const float4*)src)[i];
  union { ushort_t u[4]; unsigned long long ll; } o;
  o.u[0] = f2bf(v.x); o.u[1] = f2bf(v.y); o.u[2] = f2bf(v.z); o.u[3] = f2bf(v.w);
  ((unsigned long long*)dst)[i] = o.ll;
}

// src fp32 [R][C] row-major  ->  dst bf16 [C][R] row-major (row stride R)
__global__ void transpose_conv(const float* __restrict__ src, ushort_t* __restrict__ dst,
                               int R, int C) {
  __shared__ float tile[32][33];
  int c0 = blockIdx.x * 32, r0 = blockIdx.y * 32;
  int tx = threadIdx.x, ty = threadIdx.y;
#pragma unroll
  for (int i = ty; i < 32; i += 8)
    tile[i][tx] = src[(long)(r0 + i) * C + c0 + tx];
  __syncthreads();
#pragma unroll
  for (int i = ty; i < 32; i += 8)
    dst[(long)(c0 + i) * R + r0 + tx] = f2bf(tile[tx][i]);
}

// ---------------- GEMM: C[M,N] = A[M,K] * B^T (B stored [N][K]), 64x128 tile ----------------
// LDS chunk-major: slot16(As) = (rowtile*4 + quad)*16 + m  -> fragment reads are base+lane*16
// EPI=0: QKV epilogue (N=3072): n<2048 -> q_buf [32][2048][64] (scaled QSCALE),
//        n<2560 -> k_buf [8][2048][64], else v^T buf [8][64][2048]
// EPI=1: fp32 C output
template <int EPI>
__global__ __launch_bounds__(256, 3) void gemm_bt(
    const ushort_t* __restrict__ A, const ushort_t* __restrict__ B,
    float* __restrict__ C,
    ushort_t* __restrict__ qb, ushort_t* __restrict__ kb, ushort_t* __restrict__ vb,
    int M, int N, int K) {
  __shared__ ushort_t As[64 * 32];    // 256 slots of 16B
  __shared__ ushort_t Bs[128 * 32];   // 512 slots
  const int t = threadIdx.x;
  const int w = t >> 6, lane = t & 63;
  const int m = lane & 15, quad = lane >> 4;
  const int m0 = blockIdx.y * 64, n0 = blockIdx.x * 128;
  const int wr = w >> 1, wc = w & 1;

  floatx4 acc[2][4] = {};

  for (int kk = 0; kk < K; kk += 32) {
    __syncthreads();
    {
      int s = t;
      int m_ = s & 15, qd = (s >> 4) & 3, rt = s >> 6;
      gl_lds16(A + (long)(m0 + rt * 16 + m_) * K + kk + qd * 8, As + s * 8);
    }
#pragma unroll
    for (int i = 0; i < 2; ++i) {
      int s = i * 256 + t;
      int m_ = s & 15, qd = (s >> 4) & 3, ntl = s >> 6;
      gl_lds16(B + (long)(n0 + ntl * 16 + m_) * K + kk + qd * 8, Bs + s * 8);
    }
    __syncthreads();
    short8 af[2], bf[4];
#pragma unroll
    for (int i = 0; i < 2; ++i)
      af[i] = *(const short8*)(As + ((wr * 2 + i) * 64 + lane) * 8);
#pragma unroll
    for (int j = 0; j < 4; ++j)
      bf[j] = *(const short8*)(Bs + ((wc * 4 + j) * 64 + lane) * 8);
#pragma unroll
    for (int i = 0; i < 2; ++i)
#pragma unroll
      for (int j = 0; j < 4; ++j)
        acc[i][j] = MFMA32(af[i], bf[j], acc[i][j]);
  }

#pragma unroll
  for (int i = 0; i < 2; ++i)
#pragma unroll
    for (int j = 0; j < 4; ++j)
#pragma unroll
      for (int r = 0; r < 4; ++r) {
        float v = acc[i][j][r];
        int row = m0 + wr * 32 + i * 16 + quad * 4 + r;
        int col = n0 + wc * 64 + j * 16 + m;
        if (EPI == 1) {
          C[(long)row * N + col] = v;
        } else {
          if (col < 2048) {
            qb[((((col >> 6) * 2048) + row) << 6) | (col & 63)] = f2bf(v * QSCALE);
          } else if (col < 2560) {
            int g = (col - 2048) >> 6;
            kb[(((g * 2048) + row) << 6) | (col & 63)] = f2bf(v);
          } else {
            int g = (col - 2560) >> 6;
            vb[(long)((g << 6) | (col & 63)) * 2048 + row] = f2bf(v);
          }
        }
      }
}

// ---------------- flash attention, S^T orientation ----------------
// Q [32][S][64] bf16 (pre-scaled by QSCALE), K [8][S][64] bf16, V^T [8][64][S] bf16
// -> O [S][2048] bf16.  Per wave: 32 q-columns (2 nt tiles).  S^T = K*Q^T so each lane
// holds ONE q-row; P^T stays in registers in the MFMA B-operand layout.  PV uses K=32
// MFMAs over a custom K-permutation pairing two 16-row t-tiles: B = concat of two
// C-layout P fragments (lo/hi), A = two ds_read_b64 of V^T from LDS shuffled together.
__global__ __launch_bounds__(256, 2) void flash_kernel(
    const ushort_t* __restrict__ Q, const ushort_t* __restrict__ Kb,
    const ushort_t* __restrict__ Vb, ushort_t* __restrict__ O, int S) {
  __shared__ ushort_t Ks[2 * 128 * 32];  // slot16 = ((kq*8+mt)*4+quad)*16+m
  __shared__ ushort_t Vs[64 * 128];      // slot16 = ((mt*2+th)*4+ct)*16+m
  const int t = threadIdx.x;
  const int w = t >> 6, lane = t & 63;
  const int n = lane & 15, quad = lane >> 4;
  const int h = blockIdx.y, g = h >> 2;
  const int q0 = blockIdx.x * 128 + w * 32;
  const ushort_t* qp = Q + (long)h * S * 64;
  const ushort_t* kp = Kb + (long)g * S * 64;
  const ushort_t* vp = Vb + (long)g * 64 * S;

  short8 qf[2][2];  // B-operand: lane n = q, k = d
#pragma unroll
  for (int nt = 0; nt < 2; ++nt)
#pragma unroll
    for (int kq = 0; kq < 2; ++kq)
      qf[nt][kq] = *(const short8*)(qp + (long)(q0 + nt * 16 + n) * 64 + kq * 32 + quad * 8);

  float mrow[2] = {-3e38f, -3e38f};
  float lrow[2] = {0.f, 0.f};
  floatx4 oacc[2][4] = {};
  short8 ones8;
#pragma unroll
  for (int i = 0; i < 8; ++i) ones8[i] = (short)0x3F80;  // bf16 1.0

  for (int t0 = 0; t0 < S; t0 += 128) {
    __syncthreads();
#pragma unroll
    for (int i = 0; i < 4; ++i) {
      int s = i * 256 + t;
      int m_ = s & 15, qd = (s >> 4) & 3, mt = (s >> 6) & 7, kq = s >> 9;
      gl_lds16(kp + (long)(t0 + mt * 16 + m_) * 64 + kq * 32 + qd * 8, Ks + s * 8);
    }
#pragma unroll
    for (int i = 0; i < 4; ++i) {
      int s = i * 256 + t;
      int m_ = s & 15, ct = (s >> 4) & 3, th = (s >> 6) & 1, mt = s >> 7;
      gl_lds16(vp + (long)(ct * 16 + m_) * S + t0 + mt * 16 + th * 8, Vs + s * 8);
    }
    __syncthreads();

    // S^T tiles: sacc[nt][mt], col = q (lane n), row = t_local = quad*4+r
    floatx4 sacc[2][8] = {};
#pragma unroll
    for (int mt = 0; mt < 8; ++mt) {
      short8 a0 = *(const short8*)(Ks + (mt * 64 + lane) * 8);
      short8 a1 = *(const short8*)(Ks + ((8 + mt) * 64 + lane) * 8);
#pragma unroll
      for (int nt = 0; nt < 2; ++nt) {
        sacc[nt][mt] = MFMA32(a0, qf[nt][0], sacc[nt][mt]);
        sacc[nt][mt] = MFMA32(a1, qf[nt][1], sacc[nt][mt]);
      }
    }

    // online softmax in log2 domain; P^T packed in-register.
    // P8[nt][p]: lo half = P fragment of tile 2p, hi half = tile 2p+1.
    short8 P8[2][4];
#pragma unroll
    for (int nt = 0; nt < 2; ++nt) {
      float mx = -3e38f;
#pragma unroll
      for (int mt = 0; mt < 8; ++mt)
#pragma unroll
        for (int r = 0; r < 4; ++r) mx = fmaxf(mx, sacc[nt][mt][r]);
      mx = fmaxf(mx, __shfl_xor(mx, 16));
      mx = fmaxf(mx, __shfl_xor(mx, 32));
      float mnew = fmaxf(mrow[nt], mx);
      float alpha = exp2_(mrow[nt] - mnew);
      mrow[nt] = mnew;
#pragma unroll
      for (int mt = 0; mt < 8; ++mt) {
        int p = mt >> 1, hh = (mt & 1) * 4;
#pragma unroll
        for (int r = 0; r < 4; ++r)
          P8[nt][p][hh + r] = (short)f2bf(exp2_(sacc[nt][mt][r] - mnew));
      }
      // l via ones-MFMA: cross-quad t-sum done by the matrix pipe
      floatx4 lacc = {};
#pragma unroll
      for (int p = 0; p < 4; ++p)
        lacc = MFMA32(ones8, P8[nt][p], lacc);
      lrow[nt] = lrow[nt] * alpha + lacc[0];
#pragma unroll
      for (int ct = 0; ct < 4; ++ct)
#pragma unroll
        for (int r = 0; r < 4; ++r) oacc[nt][ct][r] *= alpha;
    }

    // O^T += V^T * P^T   (A = V^T from LDS: lo = tile 2p, hi = tile 2p+1)
#pragma unroll
    for (int p = 0; p < 4; ++p) {
      short8 vf[4];
#pragma unroll
      for (int ct = 0; ct < 4; ++ct) {
        bf16x4 lo = *(const bf16x4*)(Vs + (((2 * p) * 2 + (quad >> 1)) * 4 + ct) * 128 + n * 8 + (quad & 1) * 4);
        bf16x4 hi = *(const bf16x4*)(Vs + (((2 * p + 1) * 2 + (quad >> 1)) * 4 + ct) * 128 + n * 8 + (quad & 1) * 4);
        vf[ct] = __builtin_shufflevector(lo, hi, 0, 1, 2, 3, 4, 5, 6, 7);
      }
#pragma unroll
      for (int nt = 0; nt < 2; ++nt)
#pragma unroll
        for (int ct = 0; ct < 4; ++ct)
          oacc[nt][ct] = MFMA32(vf[ct], P8[nt][p], oacc[nt][ct]);
    }
  }

#pragma unroll
  for (int nt = 0; nt < 2; ++nt) {
    float inv = 1.f / lrow[nt];
    int q = q0 + nt * 16 + n;
#pragma unroll
    for (int ct = 0; ct < 4; ++ct) {
      bf16x4 o4;
#pragma unroll
      for (int r = 0; r < 4; ++r) o4[r] = (short)f2bf(oacc[nt][ct][r] * inv);
      *(bf16x4*)(O + (long)q * 2048 + h * 64 + ct * 16 + quad * 4) = o4;
    }
  }
}

// ---------------- launch ----------------

extern "C" void kernel_launch(void* const* d_in, const int* in_sizes, int n_in,
                              void* d_out, int out_size, void* d_ws, size_t ws_size,
                              hipStream_t stream) {
  (void)in_sizes; (void)n_in; (void)out_size; (void)ws_size;
  const float* x  = (const float*)d_in[0];
  const float* wq = (const float*)d_in[1];
  const float* wk = (const float*)d_in[2];
  const float* wv = (const float*)d_in[3];
  const float* wo = (const float*)d_in[4];
  float* out = (float*)d_out;
  char* ws = (char*)d_ws;
  const size_t MB = 1u << 20;

  ushort_t* xb    = (ushort_t*)(ws);            // 8 MB  x bf16 [2048][2048]
  ushort_t* wqkvT = (ushort_t*)(ws + 8 * MB);   // 12 MB [3072][2048]
  ushort_t* woT   = (ushort_t*)(ws + 20 * MB);  // 8 MB  [2048][2048]
  ushort_t* qbuf  = (ushort_t*)(ws + 28 * MB);  // 8 MB  [32][2048][64]
  ushort_t* kbuf  = (ushort_t*)(ws + 36 * MB);  // 2 MB  [8][2048][64]
  ushort_t* vbuf  = (ushort_t*)(ws + 38 * MB);  // 2 MB  [8][64][2048]
  ushort_t* attn  = xb;                         // alias: xb dead after gemm<0>

  conv_x_kernel<<<4096, 256, 0, stream>>>(x, xb, 2048 * 2048 / 4);
  dim3 tb(32, 8);
  transpose_conv<<<dim3(64, 64), tb, 0, stream>>>(wq, wqkvT, 2048, 2048);
  transpose_conv<<<dim3(16, 64), tb, 0, stream>>>(wk, wqkvT + 2048 * 2048, 2048, 512);
  transpose_conv<<<dim3(16, 64), tb, 0, stream>>>(wv, wqkvT + 2560 * 2048, 2048, 512);
  transpose_conv<<<dim3(64, 64), tb, 0, stream>>>(wo, woT, 2048, 2048);

  gemm_bt<0><<<dim3(24, 32), 256, 0, stream>>>(xb, wqkvT, nullptr, qbuf, kbuf, vbuf,
                                               2048, 3072, 2048);
  flash_kernel<<<dim3(16, 32), 256, 0, stream>>>(qbuf, kbuf, vbuf, attn, 2048);
  gemm_bt<1><<<dim3(16, 32), 256, 0, stream>>>(attn, woT, out, nullptr, nullptr, nullptr,
                                               2048, 2048, 2048);
}

// Round 5
// 293.863 us; speedup vs baseline: 1.0218x; 1.0218x over previous
//
#include <hip/hip_runtime.h>

typedef unsigned short ushort_t;
typedef __attribute__((ext_vector_type(8))) short short8;
typedef __attribute__((ext_vector_type(4))) short bf16x4;
typedef __attribute__((ext_vector_type(4))) float floatx4;

#define MFMA32(A, B, C) __builtin_amdgcn_mfma_f32_16x16x32_bf16(A, B, C, 0, 0, 0)

__device__ __forceinline__ float exp2_(float x) {
#if __has_builtin(__builtin_amdgcn_exp2f)
  return __builtin_amdgcn_exp2f(x);
#else
  return __builtin_exp2f(x);
#endif
}

__device__ __forceinline__ unsigned short f2bf(float f) {
  unsigned int u = __float_as_uint(f);
  u += 0x7fffu + ((u >> 16) & 1u);
  return (unsigned short)(u >> 16);
}

__device__ __forceinline__ void gl_lds16(const void* g, void* l) {
  __builtin_amdgcn_global_load_lds((const __attribute__((address_space(1))) void*)g,
                                   (__attribute__((address_space(3))) void*)l,
                                   16, 0, 0);
}

// 0.125 (1/sqrt(64)) * log2(e): scores land in log2 domain for v_exp_f32
#define QSCALE 0.18033688011112042f

// ---------------- prep kernels ----------------

__global__ void conv_x_kernel(const float* __restrict__ src, ushort_t* __restrict__ dst, int n4) {
  int i = blockIdx.x * blockDim.x + threadIdx.x;
  if (i >= n4) return;
  float4 v = ((const float4*)src)[i];
  union { ushort_t u[4]; unsigned long long ll; } o;
  o.u[0] = f2bf(v.x); o.u[1] = f2bf(v.y); o.u[2] = f2bf(v.z); o.u[3] = f2bf(v.w);
  ((unsigned long long*)dst)[i] = o.ll;
}

// src fp32 [R][C] row-major  ->  dst bf16 [C][R] row-major (row stride R)
__global__ void transpose_conv(const float* __restrict__ src, ushort_t* __restrict__ dst,
                               int R, int C) {
  __shared__ float tile[32][33];
  int c0 = blockIdx.x * 32, r0 = blockIdx.y * 32;
  int tx = threadIdx.x, ty = threadIdx.y;
#pragma unroll
  for (int i = ty; i < 32; i += 8)
    tile[i][tx] = src[(long)(r0 + i) * C + c0 + tx];
  __syncthreads();
#pragma unroll
  for (int i = ty; i < 32; i += 8)
    dst[(long)(c0 + i) * R + r0 + tx] = f2bf(tile[tx][i]);
}

// ---------------- GEMM: C[M,N] = A[M,K] * B^T (B stored [N][K]), 64x128 tile, BK=64 ----------------
// Chunk-major LDS slots: slot = rt*128 + ks*64 + quad*16 + m  (16B each).
// Fragment read for (rt,ks) = base + lane*16B -> conflict-free; 16 MFMAs per barrier.
// EPI=0: QKV epilogue (N=3072): n<2048 -> q_buf [32][2048][64] (scaled QSCALE),
//        n<2560 -> k_buf [8][2048][64], else v^T buf [8][64][2048]
// EPI=1: fp32 C output
template <int EPI>
__global__ __launch_bounds__(256, 3) void gemm_bt(
    const ushort_t* __restrict__ A, const ushort_t* __restrict__ B,
    float* __restrict__ C,
    ushort_t* __restrict__ qb, ushort_t* __restrict__ kb, ushort_t* __restrict__ vb,
    int M, int N, int K) {
  __shared__ ushort_t As[64 * 64];    // 512 slots of 16B
  __shared__ ushort_t Bs[128 * 64];   // 1024 slots
  const int t = threadIdx.x;
  const int w = t >> 6, lane = t & 63;
  const int m = lane & 15, quad = lane >> 4;
  const int m0 = blockIdx.y * 64, n0 = blockIdx.x * 128;
  const int wr = w >> 1, wc = w & 1;

  floatx4 acc[2][4] = {};

  for (int kk = 0; kk < K; kk += 64) {
    __syncthreads();
#pragma unroll
    for (int i = 0; i < 2; ++i) {
      int s = i * 256 + t;
      int m_ = s & 15, qd = (s >> 4) & 3, ks = (s >> 6) & 1, rt = s >> 7;
      gl_lds16(A + (long)(m0 + rt * 16 + m_) * K + kk + ks * 32 + qd * 8, As + s * 8);
    }
#pragma unroll
    for (int i = 0; i < 4; ++i) {
      int s = i * 256 + t;
      int m_ = s & 15, qd = (s >> 4) & 3, ks = (s >> 6) & 1, rt = s >> 7;
      gl_lds16(B + (long)(n0 + rt * 16 + m_) * K + kk + ks * 32 + qd * 8, Bs + s * 8);
    }
    __syncthreads();
    short8 af[2][2], bf[4][2];
#pragma unroll
    for (int i = 0; i < 2; ++i)
#pragma unroll
      for (int ks = 0; ks < 2; ++ks)
        af[i][ks] = *(const short8*)(As + (((wr * 2 + i) * 8 + ks * 4) * 16 + lane) * 8);
#pragma unroll
    for (int j = 0; j < 4; ++j)
#pragma unroll
      for (int ks = 0; ks < 2; ++ks)
        bf[j][ks] = *(const short8*)(Bs + (((wc * 4 + j) * 8 + ks * 4) * 16 + lane) * 8);
#pragma unroll
    for (int i = 0; i < 2; ++i)
#pragma unroll
      for (int j = 0; j < 4; ++j) {
        acc[i][j] = MFMA32(af[i][0], bf[j][0], acc[i][j]);
        acc[i][j] = MFMA32(af[i][1], bf[j][1], acc[i][j]);
      }
  }

#pragma unroll
  for (int i = 0; i < 2; ++i)
#pragma unroll
    for (int j = 0; j < 4; ++j)
#pragma unroll
      for (int r = 0; r < 4; ++r) {
        float v = acc[i][j][r];
        int row = m0 + wr * 32 + i * 16 + quad * 4 + r;
        int col = n0 + wc * 64 + j * 16 + m;
        if (EPI == 1) {
          C[(long)row * N + col] = v;
        } else {
          if (col < 2048) {
            qb[((((col >> 6) * 2048) + row) << 6) | (col & 63)] = f2bf(v * QSCALE);
          } else if (col < 2560) {
            int g = (col - 2048) >> 6;
            kb[(((g * 2048) + row) << 6) | (col & 63)] = f2bf(v);
          } else {
            int g = (col - 2560) >> 6;
            vb[(long)((g << 6) | (col & 63)) * 2048 + row] = f2bf(v);
          }
        }
      }
}

// ---------------- flash attention, S^T orientation ----------------
// Q [32][S][64] bf16 (pre-scaled by QSCALE), K [8][S][64] bf16, V^T [8][64][S] bf16
// -> O [S][2048] bf16.  Per wave: 32 q-columns (2 nt tiles).  S^T = K*Q^T so each lane
// holds ONE q-row; P^T stays in registers in the MFMA B-operand layout.  PV uses K=32
// MFMAs over a custom K-permutation pairing two 16-row t-tiles: B = concat of two
// C-layout P fragments (lo/hi), A = two ds_read_b64 of V^T from LDS shuffled together.
__global__ __launch_bounds__(256, 2) void flash_kernel(
    const ushort_t* __restrict__ Q, const ushort_t* __restrict__ Kb,
    const ushort_t* __restrict__ Vb, ushort_t* __restrict__ O, int S) {
  __shared__ ushort_t Ks[2 * 128 * 32];  // slot16 = ((kq*8+mt)*4+quad)*16+m
  __shared__ ushort_t Vs[64 * 128];      // slot16 = ((mt*2+th)*4+ct)*16+m
  const int t = threadIdx.x;
  const int w = t >> 6, lane = t & 63;
  const int n = lane & 15, quad = lane >> 4;
  const int h = blockIdx.y, g = h >> 2;
  const int q0 = blockIdx.x * 128 + w * 32;
  const ushort_t* qp = Q + (long)h * S * 64;
  const ushort_t* kp = Kb + (long)g * S * 64;
  const ushort_t* vp = Vb + (long)g * 64 * S;

  short8 qf[2][2];  // B-operand: lane n = q, k = d
#pragma unroll
  for (int nt = 0; nt < 2; ++nt)
#pragma unroll
    for (int kq = 0; kq < 2; ++kq)
      qf[nt][kq] = *(const short8*)(qp + (long)(q0 + nt * 16 + n) * 64 + kq * 32 + quad * 8);

  float mrow[2] = {-3e38f, -3e38f};
  float lrow[2] = {0.f, 0.f};
  floatx4 oacc[2][4] = {};
  short8 ones8;
#pragma unroll
  for (int i = 0; i < 8; ++i) ones8[i] = (short)0x3F80;  // bf16 1.0

  for (int t0 = 0; t0 < S; t0 += 128) {
    __syncthreads();
#pragma unroll
    for (int i = 0; i < 4; ++i) {
      int s = i * 256 + t;
      int m_ = s & 15, qd = (s >> 4) & 3, mt = (s >> 6) & 7, kq = s >> 9;
      gl_lds16(kp + (long)(t0 + mt * 16 + m_) * 64 + kq * 32 + qd * 8, Ks + s * 8);
    }
#pragma unroll
    for (int i = 0; i < 4; ++i) {
      int s = i * 256 + t;
      int m_ = s & 15, ct = (s >> 4) & 3, th = (s >> 6) & 1, mt = s >> 7;
      gl_lds16(vp + (long)(ct * 16 + m_) * S + t0 + mt * 16 + th * 8, Vs + s * 8);
    }
    __syncthreads();

    // S^T tiles: sacc[nt][mt], col = q (lane n), row = t_local = quad*4+r
    floatx4 sacc[2][8] = {};
#pragma unroll
    for (int mt = 0; mt < 8; ++mt) {
      short8 a0 = *(const short8*)(Ks + (mt * 64 + lane) * 8);
      short8 a1 = *(const short8*)(Ks + ((8 + mt) * 64 + lane) * 8);
#pragma unroll
      for (int nt = 0; nt < 2; ++nt) {
        sacc[nt][mt] = MFMA32(a0, qf[nt][0], sacc[nt][mt]);
        sacc[nt][mt] = MFMA32(a1, qf[nt][1], sacc[nt][mt]);
      }
    }

    // online softmax in log2 domain; P^T packed in-register.
    // P8[nt][p]: lo half = P fragment of tile 2p, hi half = tile 2p+1.
    short8 P8[2][4];
#pragma unroll
    for (int nt = 0; nt < 2; ++nt) {
      float mx = -3e38f;
#pragma unroll
      for (int mt = 0; mt < 8; ++mt)
#pragma unroll
        for (int r = 0; r < 4; ++r) mx = fmaxf(mx, sacc[nt][mt][r]);
      mx = fmaxf(mx, __shfl_xor(mx, 16));
      mx = fmaxf(mx, __shfl_xor(mx, 32));
      float mnew = fmaxf(mrow[nt], mx);
      float alpha = exp2_(mrow[nt] - mnew);
      mrow[nt] = mnew;
#pragma unroll
      for (int mt = 0; mt < 8; ++mt) {
        int p = mt >> 1, hh = (mt & 1) * 4;
#pragma unroll
        for (int r = 0; r < 4; ++r)
          P8[nt][p][hh + r] = (short)f2bf(exp2_(sacc[nt][mt][r] - mnew));
      }
      // l via ones-MFMA: cross-quad t-sum done by the matrix pipe
      floatx4 lacc = {};
#pragma unroll
      for (int p = 0; p < 4; ++p)
        lacc = MFMA32(ones8, P8[nt][p], lacc);
      lrow[nt] = lrow[nt] * alpha + lacc[0];
#pragma unroll
      for (int ct = 0; ct < 4; ++ct)
#pragma unroll
        for (int r = 0; r < 4; ++r) oacc[nt][ct][r] *= alpha;
    }

    // O^T += V^T * P^T   (A = V^T from LDS: lo = tile 2p, hi = tile 2p+1)
#pragma unroll
    for (int p = 0; p < 4; ++p) {
      short8 vf[4];
#pragma unroll
      for (int ct = 0; ct < 4; ++ct) {
        bf16x4 lo = *(const bf16x4*)(Vs + (((2 * p) * 2 + (quad >> 1)) * 4 + ct) * 128 + n * 8 + (quad & 1) * 4);
        bf16x4 hi = *(const bf16x4*)(Vs + (((2 * p + 1) * 2 + (quad >> 1)) * 4 + ct) * 128 + n * 8 + (quad & 1) * 4);
        vf[ct] = __builtin_shufflevector(lo, hi, 0, 1, 2, 3, 4, 5, 6, 7);
      }
#pragma unroll
      for (int nt = 0; nt < 2; ++nt)
#pragma unroll
        for (int ct = 0; ct < 4; ++ct)
          oacc[nt][ct] = MFMA32(vf[ct], P8[nt][p], oacc[nt][ct]);
    }
  }

#pragma unroll
  for (int nt = 0; nt < 2; ++nt) {
    float inv = 1.f / lrow[nt];
    int q = q0 + nt * 16 + n;
#pragma unroll
    for (int ct = 0; ct < 4; ++ct) {
      bf16x4 o4;
#pragma unroll
      for (int r = 0; r < 4; ++r) o4[r] = (short)f2bf(oacc[nt][ct][r] * inv);
      *(bf16x4*)(O + (long)q * 2048 + h * 64 + ct * 16 + quad * 4) = o4;
    }
  }
}

// ---------------- launch ----------------

extern "C" void kernel_launch(void* const* d_in, const int* in_sizes, int n_in,
                              void* d_out, int out_size, void* d_ws, size_t ws_size,
                              hipStream_t stream) {
  (void)in_sizes; (void)n_in; (void)out_size; (void)ws_size;
  const float* x  = (const float*)d_in[0];
  const float* wq = (const float*)d_in[1];
  const float* wk = (const float*)d_in[2];
  const float* wv = (const float*)d_in[3];
  const float* wo = (const float*)d_in[4];
  float* out = (float*)d_out;
  char* ws = (char*)d_ws;
  const size_t MB = 1u << 20;

  ushort_t* xb    = (ushort_t*)(ws);            // 8 MB  x bf16 [2048][2048]
  ushort_t* wqkvT = (ushort_t*)(ws + 8 * MB);   // 12 MB [3072][2048]
  ushort_t* woT   = (ushort_t*)(ws + 20 * MB);  // 8 MB  [2048][2048]
  ushort_t* qbuf  = (ushort_t*)(ws + 28 * MB);  // 8 MB  [32][2048][64]
  ushort_t* kbuf  = (ushort_t*)(ws + 36 * MB);  // 2 MB  [8][2048][64]
  ushort_t* vbuf  = (ushort_t*)(ws + 38 * MB);  // 2 MB  [8][64][2048]
  ushort_t* attn  = xb;                         // alias: xb dead after gemm<0>

  conv_x_kernel<<<4096, 256, 0, stream>>>(x, xb, 2048 * 2048 / 4);
  dim3 tb(32, 8);
  transpose_conv<<<dim3(64, 64), tb, 0, stream>>>(wq, wqkvT, 2048, 2048);
  transpose_conv<<<dim3(16, 64), tb, 0, stream>>>(wk, wqkvT + 2048 * 2048, 2048, 512);
  transpose_conv<<<dim3(16, 64), tb, 0, stream>>>(wv, wqkvT + 2560 * 2048, 2048, 512);
  transpose_conv<<<dim3(64, 64), tb, 0, stream>>>(wo, woT, 2048, 2048);

  gemm_bt<0><<<dim3(24, 32), 256, 0, stream>>>(xb, wqkvT, nullptr, qbuf, kbuf, vbuf,
                                               2048, 3072, 2048);
  flash_kernel<<<dim3(16, 32), 256, 0, stream>>>(qbuf, kbuf, vbuf, attn, 2048);
  gemm_bt<1><<<dim3(16, 32), 256, 0, stream>>>(attn, woT, out, nullptr, nullptr, nullptr,
                                               2048, 2048, 2048);
}

// Round 6
// 292.346 us; speedup vs baseline: 1.0272x; 1.0052x over previous
//
#include <hip/hip_runtime.h>

typedef unsigned short ushort_t;
typedef __attribute__((ext_vector_type(8))) short short8;
typedef __attribute__((ext_vector_type(4))) short bf16x4;
typedef __attribute__((ext_vector_type(4))) float floatx4;
typedef __attribute__((ext_vector_type(4))) unsigned int uint4v;

#define MFMA32(A, B, C) __builtin_amdgcn_mfma_f32_16x16x32_bf16(A, B, C, 0, 0, 0)

__device__ __forceinline__ float exp2_(float x) {
#if __has_builtin(__builtin_amdgcn_exp2f)
  return __builtin_amdgcn_exp2f(x);
#else
  return __builtin_exp2f(x);
#endif
}

__device__ __forceinline__ unsigned short f2bf(float f) {
  unsigned int u = __float_as_uint(f);
  u += 0x7fffu + ((u >> 16) & 1u);
  return (unsigned short)(u >> 16);
}

__device__ __forceinline__ void gl_lds16(const void* g, void* l) {
  __builtin_amdgcn_global_load_lds((const __attribute__((address_space(1))) void*)g,
                                   (__attribute__((address_space(3))) void*)l,
                                   16, 0, 0);
}

// 0.125 (1/sqrt(64)) * log2(e): scores land in log2 domain for v_exp_f32
#define QSCALE 0.18033688011112042f

// ---------------- prep kernels ----------------

__global__ void conv_x_kernel(const float* __restrict__ src, ushort_t* __restrict__ dst, int n4) {
  int i = blockIdx.x * blockDim.x + threadIdx.x;
  if (i >= n4) return;
  float4 v = ((const float4*)src)[i];
  union { ushort_t u[4]; unsigned long long ll; } o;
  o.u[0] = f2bf(v.x); o.u[1] = f2bf(v.y); o.u[2] = f2bf(v.z); o.u[3] = f2bf(v.w);
  ((unsigned long long*)dst)[i] = o.ll;
}

// src fp32 [R][C] row-major  ->  dst bf16 [C][R] row-major (row stride R)
__global__ void transpose_conv(const float* __restrict__ src, ushort_t* __restrict__ dst,
                               int R, int C) {
  __shared__ float tile[32][33];
  int c0 = blockIdx.x * 32, r0 = blockIdx.y * 32;
  int tx = threadIdx.x, ty = threadIdx.y;
#pragma unroll
  for (int i = ty; i < 32; i += 8)
    tile[i][tx] = src[(long)(r0 + i) * C + c0 + tx];
  __syncthreads();
#pragma unroll
  for (int i = ty; i < 32; i += 8)
    dst[(long)(c0 + i) * R + r0 + tx] = f2bf(tile[tx][i]);
}

// ---------------- GEMM: C[M,N] = A[M,K] * B^T (B stored [N][K]) ----------------
// 128x128 tile, BK=64, register-staged pipeline:
//   issue next-tile global loads -> VGPRs, compute current tile from LDS (loads in
//   flight during compute), barrier, ds_write regs -> LDS, barrier.
// Chunk-major LDS slots (16B): slot = rt*128 + ks*64 + quad*16 + m; both the
// ds_write (lane-consecutive) and fragment ds_read_b128 (base + lane*16) are
// conflict-free.  32 MFMAs per wave per iteration (4x4 x 2 k-steps).
// EPI=0: QKV epilogue (N=3072): n<2048 -> q_buf [32][2048][64] (scaled QSCALE),
//        n<2560 -> k_buf [8][2048][64], else v^T buf [8][64][2048]
// EPI=1: fp32 C output
template <int EPI>
__global__ __launch_bounds__(256, 2) void gemm_bt(
    const ushort_t* __restrict__ A, const ushort_t* __restrict__ B,
    float* __restrict__ C,
    ushort_t* __restrict__ qb, ushort_t* __restrict__ kb, ushort_t* __restrict__ vb,
    int M, int N, int K) {
  __shared__ __align__(16) ushort_t As[128 * 64];  // 1024 slots of 16B
  __shared__ __align__(16) ushort_t Bs[128 * 64];
  const int t = threadIdx.x;
  const int w = t >> 6, lane = t & 63;
  const int m = lane & 15, quad = lane >> 4;
  const int m0 = blockIdx.y * 128, n0 = blockIdx.x * 128;
  const int wr = w >> 1, wc = w & 1;

  floatx4 acc[4][4] = {};
  uint4v ra[4], rb[4];

  // prologue: tile 0 -> regs -> LDS
#pragma unroll
  for (int i = 0; i < 4; ++i) {
    int s = i * 256 + t;
    int m_ = s & 15, qd = (s >> 4) & 3, ks = (s >> 6) & 1, rt = s >> 7;
    long off = (long)(rt * 16 + m_) * K + ks * 32 + qd * 8;
    ra[i] = *(const uint4v*)(A + (long)m0 * K + off);
    rb[i] = *(const uint4v*)(B + (long)n0 * K + off);
  }
#pragma unroll
  for (int i = 0; i < 4; ++i) {
    int s = i * 256 + t;
    *(uint4v*)(As + s * 8) = ra[i];
    *(uint4v*)(Bs + s * 8) = rb[i];
  }
  __syncthreads();

  for (int kk = 0; kk < K; kk += 64) {
    const int kn = kk + 64;
    if (kn < K) {
      // issue next tile's loads; they stay in flight during the MFMA block below
#pragma unroll
      for (int i = 0; i < 4; ++i) {
        int s = i * 256 + t;
        int m_ = s & 15, qd = (s >> 4) & 3, ks = (s >> 6) & 1, rt = s >> 7;
        long off = (long)(rt * 16 + m_) * K + kn + ks * 32 + qd * 8;
        ra[i] = *(const uint4v*)(A + (long)m0 * K + off);
        rb[i] = *(const uint4v*)(B + (long)n0 * K + off);
      }
    }
    // compute current tile from LDS
#pragma unroll
    for (int ks = 0; ks < 2; ++ks) {
      short8 af[4], bf[4];
#pragma unroll
      for (int i = 0; i < 4; ++i)
        af[i] = *(const short8*)(As + (((wr * 4 + i) * 2 + ks) * 64 + lane) * 8);
#pragma unroll
      for (int j = 0; j < 4; ++j)
        bf[j] = *(const short8*)(Bs + (((wc * 4 + j) * 2 + ks) * 64 + lane) * 8);
#pragma unroll
      for (int i = 0; i < 4; ++i)
#pragma unroll
        for (int j = 0; j < 4; ++j)
          acc[i][j] = MFMA32(af[i], bf[j], acc[i][j]);
    }
    __syncthreads();
    if (kn < K) {
#pragma unroll
      for (int i = 0; i < 4; ++i) {
        int s = i * 256 + t;
        *(uint4v*)(As + s * 8) = ra[i];
        *(uint4v*)(Bs + s * 8) = rb[i];
      }
      __syncthreads();
    }
  }

#pragma unroll
  for (int i = 0; i < 4; ++i)
#pragma unroll
    for (int j = 0; j < 4; ++j)
#pragma unroll
      for (int r = 0; r < 4; ++r) {
        float v = acc[i][j][r];
        int row = m0 + wr * 64 + i * 16 + quad * 4 + r;
        int col = n0 + wc * 64 + j * 16 + m;
        if (EPI == 1) {
          C[(long)row * N + col] = v;
        } else {
          if (col < 2048) {
            qb[((((col >> 6) * 2048) + row) << 6) | (col & 63)] = f2bf(v * QSCALE);
          } else if (col < 2560) {
            int g = (col - 2048) >> 6;
            kb[(((g * 2048) + row) << 6) | (col & 63)] = f2bf(v);
          } else {
            int g = (col - 2560) >> 6;
            vb[(long)((g << 6) | (col & 63)) * 2048 + row] = f2bf(v);
          }
        }
      }
}

// LDS slot note: fragment read slot = (rt*2 + ks)*64 + lane where rt = wr*4+i.
// Staging decode writes slot s with rt = s>>7, ks = (s>>6)&1 -> same linearization
// (rt*128 + ks*64 + quad*16 + m).  Conflict-free both directions.

// ---------------- flash attention, S^T orientation ----------------
// Q [32][S][64] bf16 (pre-scaled by QSCALE), K [8][S][64] bf16, V^T [8][64][S] bf16
// -> O [S][2048] bf16.  Per wave: 32 q-columns (2 nt tiles).  S^T = K*Q^T so each lane
// holds ONE q-row; P^T stays in registers in the MFMA B-operand layout.  PV uses K=32
// MFMAs over a custom K-permutation pairing two 16-row t-tiles: B = concat of two
// C-layout P fragments (lo/hi), A = two ds_read_b64 of V^T from LDS shuffled together.
__global__ __launch_bounds__(256, 2) void flash_kernel(
    const ushort_t* __restrict__ Q, const ushort_t* __restrict__ Kb,
    const ushort_t* __restrict__ Vb, ushort_t* __restrict__ O, int S) {
  __shared__ ushort_t Ks[2 * 128 * 32];  // slot16 = ((kq*8+mt)*4+quad)*16+m
  __shared__ ushort_t Vs[64 * 128];      // slot16 = ((mt*2+th)*4+ct)*16+m
  const int t = threadIdx.x;
  const int w = t >> 6, lane = t & 63;
  const int n = lane & 15, quad = lane >> 4;
  const int h = blockIdx.y, g = h >> 2;
  const int q0 = blockIdx.x * 128 + w * 32;
  const ushort_t* qp = Q + (long)h * S * 64;
  const ushort_t* kp = Kb + (long)g * S * 64;
  const ushort_t* vp = Vb + (long)g * 64 * S;

  short8 qf[2][2];  // B-operand: lane n = q, k = d
#pragma unroll
  for (int nt = 0; nt < 2; ++nt)
#pragma unroll
    for (int kq = 0; kq < 2; ++kq)
      qf[nt][kq] = *(const short8*)(qp + (long)(q0 + nt * 16 + n) * 64 + kq * 32 + quad * 8);

  float mrow[2] = {-3e38f, -3e38f};
  float lrow[2] = {0.f, 0.f};
  floatx4 oacc[2][4] = {};
  short8 ones8;
#pragma unroll
  for (int i = 0; i < 8; ++i) ones8[i] = (short)0x3F80;  // bf16 1.0

  for (int t0 = 0; t0 < S; t0 += 128) {
    __syncthreads();
#pragma unroll
    for (int i = 0; i < 4; ++i) {
      int s = i * 256 + t;
      int m_ = s & 15, qd = (s >> 4) & 3, mt = (s >> 6) & 7, kq = s >> 9;
      gl_lds16(kp + (long)(t0 + mt * 16 + m_) * 64 + kq * 32 + qd * 8, Ks + s * 8);
    }
#pragma unroll
    for (int i = 0; i < 4; ++i) {
      int s = i * 256 + t;
      int m_ = s & 15, ct = (s >> 4) & 3, th = (s >> 6) & 1, mt = s >> 7;
      gl_lds16(vp + (long)(ct * 16 + m_) * S + t0 + mt * 16 + th * 8, Vs + s * 8);
    }
    __syncthreads();

    // S^T tiles: sacc[nt][mt], col = q (lane n), row = t_local = quad*4+r
    floatx4 sacc[2][8] = {};
#pragma unroll
    for (int mt = 0; mt < 8; ++mt) {
      short8 a0 = *(const short8*)(Ks + (mt * 64 + lane) * 8);
      short8 a1 = *(const short8*)(Ks + ((8 + mt) * 64 + lane) * 8);
#pragma unroll
      for (int nt = 0; nt < 2; ++nt) {
        sacc[nt][mt] = MFMA32(a0, qf[nt][0], sacc[nt][mt]);
        sacc[nt][mt] = MFMA32(a1, qf[nt][1], sacc[nt][mt]);
      }
    }

    // online softmax in log2 domain; P^T packed in-register.
    // P8[nt][p]: lo half = P fragment of tile 2p, hi half = tile 2p+1.
    short8 P8[2][4];
#pragma unroll
    for (int nt = 0; nt < 2; ++nt) {
      float mx = -3e38f;
#pragma unroll
      for (int mt = 0; mt < 8; ++mt)
#pragma unroll
        for (int r = 0; r < 4; ++r) mx = fmaxf(mx, sacc[nt][mt][r]);
      mx = fmaxf(mx, __shfl_xor(mx, 16));
      mx = fmaxf(mx, __shfl_xor(mx, 32));
      float mnew = fmaxf(mrow[nt], mx);
      float alpha = exp2_(mrow[nt] - mnew);
      mrow[nt] = mnew;
#pragma unroll
      for (int mt = 0; mt < 8; ++mt) {
        int p = mt >> 1, hh = (mt & 1) * 4;
#pragma unroll
        for (int r = 0; r < 4; ++r)
          P8[nt][p][hh + r] = (short)f2bf(exp2_(sacc[nt][mt][r] - mnew));
      }
      // l via ones-MFMA: cross-quad t-sum done by the matrix pipe
      floatx4 lacc = {};
#pragma unroll
      for (int p = 0; p < 4; ++p)
        lacc = MFMA32(ones8, P8[nt][p], lacc);
      lrow[nt] = lrow[nt] * alpha + lacc[0];
#pragma unroll
      for (int ct = 0; ct < 4; ++ct)
#pragma unroll
        for (int r = 0; r < 4; ++r) oacc[nt][ct][r] *= alpha;
    }

    // O^T += V^T * P^T   (A = V^T from LDS: lo = tile 2p, hi = tile 2p+1)
#pragma unroll
    for (int p = 0; p < 4; ++p) {
      short8 vf[4];
#pragma unroll
      for (int ct = 0; ct < 4; ++ct) {
        bf16x4 lo = *(const bf16x4*)(Vs + (((2 * p) * 2 + (quad >> 1)) * 4 + ct) * 128 + n * 8 + (quad & 1) * 4);
        bf16x4 hi = *(const bf16x4*)(Vs + (((2 * p + 1) * 2 + (quad >> 1)) * 4 + ct) * 128 + n * 8 + (quad & 1) * 4);
        vf[ct] = __builtin_shufflevector(lo, hi, 0, 1, 2, 3, 4, 5, 6, 7);
      }
#pragma unroll
      for (int nt = 0; nt < 2; ++nt)
#pragma unroll
        for (int ct = 0; ct < 4; ++ct)
          oacc[nt][ct] = MFMA32(vf[ct], P8[nt][p], oacc[nt][ct]);
    }
  }

#pragma unroll
  for (int nt = 0; nt < 2; ++nt) {
    float inv = 1.f / lrow[nt];
    int q = q0 + nt * 16 + n;
#pragma unroll
    for (int ct = 0; ct < 4; ++ct) {
      bf16x4 o4;
#pragma unroll
      for (int r = 0; r < 4; ++r) o4[r] = (short)f2bf(oacc[nt][ct][r] * inv);
      *(bf16x4*)(O + (long)q * 2048 + h * 64 + ct * 16 + quad * 4) = o4;
    }
  }
}

// ---------------- launch ----------------

extern "C" void kernel_launch(void* const* d_in, const int* in_sizes, int n_in,
                              void* d_out, int out_size, void* d_ws, size_t ws_size,
                              hipStream_t stream) {
  (void)in_sizes; (void)n_in; (void)out_size; (void)ws_size;
  const float* x  = (const float*)d_in[0];
  const float* wq = (const float*)d_in[1];
  const float* wk = (const float*)d_in[2];
  const float* wv = (const float*)d_in[3];
  const float* wo = (const float*)d_in[4];
  float* out = (float*)d_out;
  char* ws = (char*)d_ws;
  const size_t MB = 1u << 20;

  ushort_t* xb    = (ushort_t*)(ws);            // 8 MB  x bf16 [2048][2048]
  ushort_t* wqkvT = (ushort_t*)(ws + 8 * MB);   // 12 MB [3072][2048]
  ushort_t* woT   = (ushort_t*)(ws + 20 * MB);  // 8 MB  [2048][2048]
  ushort_t* qbuf  = (ushort_t*)(ws + 28 * MB);  // 8 MB  [32][2048][64]
  ushort_t* kbuf  = (ushort_t*)(ws + 36 * MB);  // 2 MB  [8][2048][64]
  ushort_t* vbuf  = (ushort_t*)(ws + 38 * MB);  // 2 MB  [8][64][2048]
  ushort_t* attn  = xb;                         // alias: xb dead after gemm<0>

  conv_x_kernel<<<4096, 256, 0, stream>>>(x, xb, 2048 * 2048 / 4);
  dim3 tb(32, 8);
  transpose_conv<<<dim3(64, 64), tb, 0, stream>>>(wq, wqkvT, 2048, 2048);
  transpose_conv<<<dim3(16, 64), tb, 0, stream>>>(wk, wqkvT + 2048 * 2048, 2048, 512);
  transpose_conv<<<dim3(16, 64), tb, 0, stream>>>(wv, wqkvT + 2560 * 2048, 2048, 512);
  transpose_conv<<<dim3(64, 64), tb, 0, stream>>>(wo, woT, 2048, 2048);

  gemm_bt<0><<<dim3(24, 16), 256, 0, stream>>>(xb, wqkvT, nullptr, qbuf, kbuf, vbuf,
                                               2048, 3072, 2048);
  flash_kernel<<<dim3(16, 32), 256, 0, stream>>>(qbuf, kbuf, vbuf, attn, 2048);
  gemm_bt<1><<<dim3(16, 16), 256, 0, stream>>>(attn, woT, out, nullptr, nullptr, nullptr,
                                               2048, 2048, 2048);
}